// Round 9
// baseline (177.091 us; speedup 1.0000x reference)
//
#include <hip/hip_runtime.h>

// VectorAttention: B=4, C=32, H=256, W=256, HID=64, all fp32 in/out.
// hid_n = (Wq1@x + b1) - (Wk1@x)|neighbor ; scores = W2@relu(LN(hid)) via MFMA.
// kh/v/Sk stored ZERO-PADDED (258x258) pixel-major bf16/f32 -> no validity logic.
// W2A/b2 prescaled by log2(e) -> exp via native v_exp_f32. LN sum precomputed
// (sum(hid) = Sq - Sk). kv writes each pixel record with BACK-TO-BACK stores
// (full-line fill -> no partial-sector write amplification).

#define HWm 65536
#define NPIX 262144
#define PW 258
#define PHW 66564   // 258*258
#define LOG2E 1.44269504088896340736f

typedef __attribute__((ext_vector_type(8))) short short8;
typedef __attribute__((ext_vector_type(4))) float f32x4;

__device__ __forceinline__ float bflo(unsigned u) { return __uint_as_float(u << 16); }
__device__ __forceinline__ float bfhi(unsigned u) { return __uint_as_float(u & 0xFFFF0000u); }
__device__ __forceinline__ unsigned packbf2(float a, float b) {
    unsigned ua = __float_as_uint(a);
    unsigned ub = __float_as_uint(b);
    ua = (ua + 0x7FFFu + ((ua >> 16) & 1u)) >> 16;          // RNE
    ub = (ub + 0x7FFFu + ((ub >> 16) & 1u)) & 0xFFFF0000u;  // RNE
    return ua | ub;
}
__device__ __forceinline__ unsigned cvtpk(float lo, float hi) {
    unsigned r;
    asm("v_cvt_pk_bf16_f32 %0, %1, %2" : "=v"(r) : "v"(lo), "v"(hi));
    return r;
}

// ---------------- kernel 0: weight prep ----------------
__global__ __launch_bounds__(256) void prep_kernel(
    const float* __restrict__ Wqkv, const float* __restrict__ W1,
    const float* __restrict__ W2, float* __restrict__ Wq1,
    float* __restrict__ Wk1, unsigned* __restrict__ W2A)
{
    const int tid = threadIdx.x;
    for (int i = tid; i < 2048; i += 256) {
        const int d = i >> 5, c = i & 31;
        float aq = 0.f, ak = 0.f;
#pragma unroll
        for (int k = 0; k < 32; ++k) {
            const float w1 = W1[d * 32 + k];
            aq = fmaf(w1, Wqkv[k * 32 + c], aq);
            ak = fmaf(w1, Wqkv[(32 + k) * 32 + c], ak);
        }
        Wq1[i] = aq;
        Wk1[i] = ak;
    }
    // W2 A-fragments (prescaled by log2e):
    // frag (ct,kb), lane l, elem j -> W2[(l&15)+16ct][kb*32+(l>>4)*8+j] * LOG2E
    for (int i = tid; i < 1024; i += 256) {
        const int w = i & 3;
        const int lane = (i >> 2) & 63;
        const int kb = (i >> 8) & 1;
        const int ct = (i >> 9) & 1;
        const int row = (lane & 15) + 16 * ct;
        const int k0 = kb * 32 + ((lane >> 4) & 3) * 8 + 2 * w;
        W2A[i] = packbf2(W2[row * 64 + k0] * LOG2E, W2[row * 64 + k0 + 1] * LOG2E);
    }
}

// ---------------- kernel 1: padded projections + stats + gate/residual ----------------
__global__ __launch_bounds__(256) void kv_kernel(
    const float* __restrict__ x, const float* __restrict__ Wqkv,
    const float* __restrict__ Wk1, const float* __restrict__ Wq1,
    const float* __restrict__ b1, const float* __restrict__ Wg,
    const float* __restrict__ bg, unsigned* __restrict__ khP,
    unsigned* __restrict__ qhg, unsigned* __restrict__ vP,
    float* __restrict__ SkP, float* __restrict__ SqG,
    float* __restrict__ out)
{
    const int bid = blockIdx.x;
    const int tid = threadIdx.x;

    if (bid >= 1024) {
        // border zeroing: 4112 border pixels (1028 per batch)
        const int t = (bid - 1024) * 256 + tid;
        if (t < 4112) {
            const int bb = t / 1028;
            const int rr = t - bb * 1028;
            int hh, ww;
            if (rr < 258)      { hh = 0;             ww = rr; }
            else if (rr < 516) { hh = 257;           ww = rr - 258; }
            else if (rr < 772) { hh = rr - 516 + 1;  ww = 0; }
            else               { hh = rr - 772 + 1;  ww = 257; }
            const size_t pixP = (size_t)bb * PHW + hh * PW + ww;
            uint4* kp = (uint4*)khP + pixP * 8;
            uint4* vp = (uint4*)vP + pixP * 4;
            const uint4 z = { 0u, 0u, 0u, 0u };
#pragma unroll
            for (int i = 0; i < 8; ++i) kp[i] = z;
#pragma unroll
            for (int i = 0; i < 4; ++i) vp[i] = z;
            SkP[pixP] = 0.f;
        }
        return;
    }

    const int pix = bid * 256 + tid;
    const int b = pix >> 16;
    const int rem = pix & 65535;
    const int h = rem >> 8;
    const int w = rem & 255;
    const size_t pixP = (size_t)b * PHW + (h + 1) * PW + (w + 1);

    const float* xp = x + (size_t)b * (32 * HWm) + rem;
    float xv[32];
#pragma unroll
    for (int c = 0; c < 32; ++c) xv[c] = xp[c * HWm];

    // ---- kh = Wk1 @ x: full record in regs, then 8 back-to-back 16B stores ----
    {
        float a[64];
#pragma unroll
        for (int d = 0; d < 64; ++d) {
            const float* wr = Wk1 + d * 32;
            float acc = 0.f;
#pragma unroll
            for (int c = 0; c < 32; ++c) acc = fmaf(wr[c], xv[c], acc);
            a[d] = acc;
        }
        uint4 u[8];
        float sk = 0.f;
#pragma unroll
        for (int g = 0; g < 8; ++g) {
            u[g].x = cvtpk(a[g * 8 + 0], a[g * 8 + 1]);
            u[g].y = cvtpk(a[g * 8 + 2], a[g * 8 + 3]);
            u[g].z = cvtpk(a[g * 8 + 4], a[g * 8 + 5]);
            u[g].w = cvtpk(a[g * 8 + 6], a[g * 8 + 7]);
            sk += bflo(u[g].x) + bfhi(u[g].x) + bflo(u[g].y) + bfhi(u[g].y)
                + bflo(u[g].z) + bfhi(u[g].z) + bflo(u[g].w) + bfhi(u[g].w);
        }
        uint4* khp = (uint4*)khP + pixP * 8;
#pragma unroll
        for (int g = 0; g < 8; ++g) khp[g] = u[g];
        SkP[pixP] = sk;
    }

    // ---- qh = Wq1 @ x + b1: same batching ----
    {
        float a[64];
#pragma unroll
        for (int d = 0; d < 64; ++d) {
            const float* wr = Wq1 + d * 32;
            float acc = b1[d];
#pragma unroll
            for (int c = 0; c < 32; ++c) acc = fmaf(wr[c], xv[c], acc);
            a[d] = acc;
        }
        uint4 u[8];
        float sq = 0.f;
#pragma unroll
        for (int g = 0; g < 8; ++g) {
            u[g].x = cvtpk(a[g * 8 + 0], a[g * 8 + 1]);
            u[g].y = cvtpk(a[g * 8 + 2], a[g * 8 + 3]);
            u[g].z = cvtpk(a[g * 8 + 4], a[g * 8 + 5]);
            u[g].w = cvtpk(a[g * 8 + 6], a[g * 8 + 7]);
            sq += bflo(u[g].x) + bfhi(u[g].x) + bflo(u[g].y) + bfhi(u[g].y)
                + bflo(u[g].z) + bfhi(u[g].z) + bflo(u[g].w) + bfhi(u[g].w);
        }
        uint4* qhp = (uint4*)qhg + (size_t)pix * 8;
#pragma unroll
        for (int g = 0; g < 8; ++g) qhp[g] = u[g];
        SqG[pix] = sq;
    }

    // ---- v = Wqkv[64:96] @ x: 4 back-to-back stores ----
    {
        float a[32];
#pragma unroll
        for (int d = 0; d < 32; ++d) {
            const float* wr = Wqkv + (64 + d) * 32;
            float acc = 0.f;
#pragma unroll
            for (int c = 0; c < 32; ++c) acc = fmaf(wr[c], xv[c], acc);
            a[d] = acc;
        }
        uint4 u[4];
#pragma unroll
        for (int g = 0; g < 4; ++g) {
            u[g].x = cvtpk(a[g * 8 + 0], a[g * 8 + 1]);
            u[g].y = cvtpk(a[g * 8 + 2], a[g * 8 + 3]);
            u[g].z = cvtpk(a[g * 8 + 4], a[g * 8 + 5]);
            u[g].w = cvtpk(a[g * 8 + 6], a[g * 8 + 7]);
        }
        uint4* vp = (uint4*)vP + pixP * 4;
#pragma unroll
        for (int g = 0; g < 4; ++g) vp[g] = u[g];
    }

    // ---- out = Wg @ x + bg + x ----
    float* outp = out + (size_t)b * (32 * HWm) + rem;
#pragma unroll 4
    for (int c = 0; c < 32; ++c) {
        float acc = bg[c];
        const float* wr = Wg + c * 32;
#pragma unroll
        for (int k = 0; k < 32; ++k) acc = fmaf(wr[k], xv[k], acc);
        outp[c * HWm] = acc + xv[c];
    }
}

// ---------------- kernel 2: MFMA attention ----------------
// 16x16 px tile / 256-thread block, 4 waves; wave-local MFMA (zero barriers).
__global__ __launch_bounds__(256) void attn_kernel(
    const unsigned* __restrict__ qhg, const unsigned* __restrict__ khP,
    const unsigned* __restrict__ vP, const short8* __restrict__ w2a,
    const float* __restrict__ SkP, const float* __restrict__ SqG,
    const float* __restrict__ lnw, const float* __restrict__ lnb,
    const float* __restrict__ b2, float* __restrict__ out)
{
    __shared__ __align__(16) char hidL[32768];

    const int tid = threadIdx.x;
    const int bid = blockIdx.x;
    const int swz = (bid & 7) * 128 + (bid >> 3);
    const int b = swz >> 8;
    const int trem = swz & 255;
    const int h0 = (trem >> 4) << 4;
    const int w0 = (trem & 15) << 4;

    const int l = tid & 63;
    const int lane15 = tid & 15;
    const int q = (tid >> 4) & 3;
    const int wrow = tid >> 6;

    const int row = tid >> 4;
    const int h = h0 + row, w = w0 + lane15;
    const int pix = (b << 16) + (h << 8) + w;
    const int pixP = b * PHW + (h + 1) * PW + (w + 1);       // padded own-pixel
    const int tileP = b * PHW + (h0 + 1) * PW + (w0 + 1);    // padded tile base

    // own-pixel qh (packed bf16) + Sq
    unsigned qw[32];
    {
        const uint4* qp = (const uint4*)qhg + (size_t)pix * 8;
#pragma unroll
        for (int i = 0; i < 8; ++i) {
            const uint4 u = qp[i];
            qw[4 * i] = u.x; qw[4 * i + 1] = u.y; qw[4 * i + 2] = u.z; qw[4 * i + 3] = u.w;
        }
    }
    const float Sq = SqG[pix];

    // A fragments (W2 * log2e), persistent
    const short8 a00 = w2a[0 * 64 + l];
    const short8 a01 = w2a[1 * 64 + l];
    const short8 a10 = w2a[2 * 64 + l];
    const short8 a11 = w2a[3 * 64 + l];

    // b2 * log2e for this lane's 8 channels
    float b2v[8];
    {
        const float4 t0 = *(const float4*)(b2 + q * 4);
        const float4 t1 = *(const float4*)(b2 + 16 + q * 4);
        b2v[0] = t0.x * LOG2E; b2v[1] = t0.y * LOG2E; b2v[2] = t0.z * LOG2E; b2v[3] = t0.w * LOG2E;
        b2v[4] = t1.x * LOG2E; b2v[5] = t1.y * LOG2E; b2v[6] = t1.z * LOG2E; b2v[7] = t1.w * LOG2E;
    }

    float ssum[32], wv[32];
#pragma unroll
    for (int i = 0; i < 32; ++i) { ssum[i] = 0.f; wv[i] = 0.f; }

    const uint4* khP4 = (const uint4*)khP;
    char* const myhid = hidL + tid * 128;
    const int myswz = (tid & 7) << 4;

#pragma unroll
    for (int n = 0; n < 9; ++n) {
        const int dy = n / 3 - 1, dx = n % 3 - 1;   // compile-time after unroll

        // ---- pass 1: hid -> packed regs, sumsq via 4 accumulators ----
        const int nofs = pixP + dy * PW + dx;
        const uint4* kp = khP4 + (size_t)nofs * 8;
        const float Sk = SkP[nofs];
        float ss0 = 0.f, ss1 = 0.f, ss2 = 0.f, ss3 = 0.f;
        uint4 hw[8];
#pragma unroll
        for (int cj = 0; cj < 8; ++cj) {
            const uint4 kc = kp[cj];
            float hd[8];
            hd[0] = bflo(qw[cj * 4 + 0]) - bflo(kc.x);
            hd[1] = bfhi(qw[cj * 4 + 0]) - bfhi(kc.x);
            hd[2] = bflo(qw[cj * 4 + 1]) - bflo(kc.y);
            hd[3] = bfhi(qw[cj * 4 + 1]) - bfhi(kc.y);
            hd[4] = bflo(qw[cj * 4 + 2]) - bflo(kc.z);
            hd[5] = bfhi(qw[cj * 4 + 2]) - bfhi(kc.z);
            hd[6] = bflo(qw[cj * 4 + 3]) - bflo(kc.w);
            hd[7] = bfhi(qw[cj * 4 + 3]) - bfhi(kc.w);
            ss0 = fmaf(hd[0], hd[0], ss0); ss1 = fmaf(hd[1], hd[1], ss1);
            ss2 = fmaf(hd[2], hd[2], ss2); ss3 = fmaf(hd[3], hd[3], ss3);
            ss0 = fmaf(hd[4], hd[4], ss0); ss1 = fmaf(hd[5], hd[5], ss1);
            ss2 = fmaf(hd[6], hd[6], ss2); ss3 = fmaf(hd[7], hd[7], ss3);
            uint4 o;
            o.x = cvtpk(hd[0], hd[1]); o.y = cvtpk(hd[2], hd[3]);
            o.z = cvtpk(hd[4], hd[5]); o.w = cvtpk(hd[6], hd[7]);
            hw[cj] = o;
        }
        const float sum = Sq - Sk;
        const float sumsq = (ss0 + ss1) + (ss2 + ss3);
        const float mean = sum * 0.015625f;
        float var = fmaf(-mean, mean, sumsq * 0.015625f);
        var = fmaxf(var, 0.f);
        const float inv = __builtin_amdgcn_rcpf(sqrtf(var) + 1e-5f);
        const float nmi = -mean * inv;

        // ---- pass 2: normalize+relu from regs, single LDS write ----
#pragma unroll
        for (int cj = 0; cj < 8; ++cj) {
            const uint4 t = hw[cj];
            float hv[8];
            hv[0] = bflo(t.x); hv[1] = bfhi(t.x);
            hv[2] = bflo(t.y); hv[3] = bfhi(t.y);
            hv[4] = bflo(t.z); hv[5] = bfhi(t.z);
            hv[6] = bflo(t.w); hv[7] = bfhi(t.w);
#pragma unroll
            for (int j = 0; j < 8; ++j) {
                float tv = fmaf(hv[j], inv, nmi);
                tv = fmaf(tv, lnw[cj * 8 + j], lnb[cj * 8 + j]);
                hv[j] = fmaxf(tv, 0.f);
            }
            uint4 o;
            o.x = cvtpk(hv[0], hv[1]); o.y = cvtpk(hv[2], hv[3]);
            o.z = cvtpk(hv[4], hv[5]); o.w = cvtpk(hv[6], hv[7]);
            *(uint4*)(myhid + ((cj * 16) ^ myswz)) = o;
        }

        // ---- MFMA + softmax accumulate (wave-local rows) ----
#pragma unroll
        for (int gg = 0; gg < 4; ++gg) {
            const int g = wrow * 4 + gg;
            const int px = g * 16 + lane15;
            const char* bp = hidL + px * 128;
            const int sw = (lane15 & 7) << 4;
            const short8 b0 = *(const short8*)(bp + ((q * 16) ^ sw));
            const short8 b1 = *(const short8*)(bp + (((4 + q) * 16) ^ sw));
            f32x4 acc0 = { b2v[0], b2v[1], b2v[2], b2v[3] };
            f32x4 acc1 = { b2v[4], b2v[5], b2v[6], b2v[7] };
            acc0 = __builtin_amdgcn_mfma_f32_16x16x32_bf16(a00, b0, acc0, 0, 0, 0);
            acc0 = __builtin_amdgcn_mfma_f32_16x16x32_bf16(a01, b1, acc0, 0, 0, 0);
            acc1 = __builtin_amdgcn_mfma_f32_16x16x32_bf16(a10, b0, acc1, 0, 0, 0);
            acc1 = __builtin_amdgcn_mfma_f32_16x16x32_bf16(a11, b1, acc1, 0, 0, 0);

            const int npP = tileP + (g + dy) * PW + (lane15 + dx);
            const unsigned* vp = vP + (size_t)npP * 16;
            const uint2 vA = *(const uint2*)(vp + q * 2);
            const uint2 vB = *(const uint2*)(vp + 8 + q * 2);
            const float va[4] = { bflo(vA.x), bfhi(vA.x), bflo(vA.y), bfhi(vA.y) };
            const float vb[4] = { bflo(vB.x), bfhi(vB.x), bflo(vB.y), bfhi(vB.y) };
#pragma unroll
            for (int r = 0; r < 4; ++r) {
                const float e0 = __builtin_amdgcn_exp2f(acc0[r]);   // prescaled by log2e
                ssum[gg * 8 + r] += e0;
                wv[gg * 8 + r] = fmaf(e0, va[r], wv[gg * 8 + r]);
                const float e1 = __builtin_amdgcn_exp2f(acc1[r]);
                ssum[gg * 8 + 4 + r] += e1;
                wv[gg * 8 + 4 + r] = fmaf(e1, vb[r], wv[gg * 8 + 4 + r]);
            }
        }
    }

    // ---- output RMW: out += softmax-weighted v ----
#pragma unroll
    for (int gg = 0; gg < 4; ++gg) {
        const int g = wrow * 4 + gg;
        float* op = out + (size_t)b * (32 * HWm) + ((h0 + g) << 8) + (w0 + lane15);
#pragma unroll
        for (int r = 0; r < 4; ++r) {
            const int ch0 = q * 4 + r;
            const int ch1 = 16 + q * 4 + r;
            op[ch0 * HWm] += wv[gg * 8 + r] * __builtin_amdgcn_rcpf(ssum[gg * 8 + r]);
            op[ch1 * HWm] += wv[gg * 8 + 4 + r] * __builtin_amdgcn_rcpf(ssum[gg * 8 + 4 + r]);
        }
    }
}

extern "C" void kernel_launch(void* const* d_in, const int* in_sizes, int n_in,
                              void* d_out, int out_size, void* d_ws, size_t ws_size,
                              hipStream_t stream) {
    const float* x    = (const float*)d_in[0];
    const float* Wqkv = (const float*)d_in[1];
    const float* W1   = (const float*)d_in[2];
    const float* b1   = (const float*)d_in[3];
    const float* lnw  = (const float*)d_in[4];
    const float* lnb  = (const float*)d_in[5];
    const float* W2   = (const float*)d_in[6];
    const float* b2   = (const float*)d_in[7];
    const float* Wg   = (const float*)d_in[8];
    const float* bg   = (const float*)d_in[9];
    float* out = (float*)d_out;

    float* ws  = (float*)d_ws;
    float* Wq1 = ws;                                 // 2048 f32
    float* Wk1 = ws + 2048;                          // 2048 f32
    unsigned* W2A = (unsigned*)(ws + 4096);          // 1024 u32
    unsigned* khP = (unsigned*)(ws + 6144);          // 4*PHW*32 u32 (padded)
    unsigned* qhg = khP + (size_t)4 * PHW * 32;      // NPIX*32 u32
    unsigned* vP  = qhg + (size_t)NPIX * 32;         // 4*PHW*16 u32 (padded)
    float* SkP = (float*)(vP + (size_t)4 * PHW * 16);// 4*PHW f32 (padded)
    float* SqG = SkP + (size_t)4 * PHW;              // NPIX f32

    prep_kernel<<<1, 256, 0, stream>>>(Wqkv, W1, W2, Wq1, Wk1, W2A);
    kv_kernel<<<1024 + 17, 256, 0, stream>>>(x, Wqkv, Wk1, Wq1, b1, Wg, bg,
                                             khP, qhg, vP, SkP, SqG, out);
    attn_kernel<<<1024, 256, 0, stream>>>(qhg, khP, vP, (const short8*)W2A,
                                          SkP, SqG, lnw, lnb, b2, out);
}

// Round 10
// 129.906 us; speedup vs baseline: 1.3632x; 1.3632x over previous
//
#include <hip/hip_runtime.h>

// VectorAttention: B=4, C=32, H=256, W=256, HID=64, all fp32 in/out.
// hid_n = (Wq1@x + b1) - (Wk1@x)|neighbor ; scores = W2@relu(LN(hid)) via MFMA.
// kv is now a per-row MFMA GEMM: Wall[192][32] = [Wk1; Wq1; Wv; Wg+I] @ x^T,
// with bias C-init and the +x residual folded into (Wg+I). kh/v/Sk zero-padded
// (258x258). W2A/b2 prescaled by log2(e) -> native v_exp_f32.

#define HWm 65536
#define NPIX 262144
#define PW 258
#define PHW 66564   // 258*258
#define LOG2E 1.44269504088896340736f

typedef __attribute__((ext_vector_type(8))) short short8;
typedef __attribute__((ext_vector_type(4))) float f32x4;

__device__ __forceinline__ float bflo(unsigned u) { return __uint_as_float(u << 16); }
__device__ __forceinline__ float bfhi(unsigned u) { return __uint_as_float(u & 0xFFFF0000u); }
__device__ __forceinline__ unsigned packbf2(float a, float b) {
    unsigned ua = __float_as_uint(a);
    unsigned ub = __float_as_uint(b);
    ua = (ua + 0x7FFFu + ((ua >> 16) & 1u)) >> 16;          // RNE
    ub = (ub + 0x7FFFu + ((ub >> 16) & 1u)) & 0xFFFF0000u;  // RNE
    return ua | ub;
}
__device__ __forceinline__ unsigned cvtpk(float lo, float hi) {
    unsigned r;
    asm("v_cvt_pk_bf16_f32 %0, %1, %2" : "=v"(r) : "v"(lo), "v"(hi));
    return r;
}

// ---------------- kernel 0: weight prep ----------------
// Wall rows: 0-63 Wk1 | 64-127 Wq1 | 128-159 Wqkv[64:96] (v) | 160-191 Wg+I
// bias rows: 64-127 -> b1 | 160-191 -> bg | else 0
__global__ __launch_bounds__(256) void prep_kernel(
    const float* __restrict__ Wqkv, const float* __restrict__ W1,
    const float* __restrict__ W2, const float* __restrict__ b1v,
    const float* __restrict__ Wg, const float* __restrict__ bgv,
    float* __restrict__ Wk1, float* __restrict__ Wq1,
    unsigned* __restrict__ W2A, unsigned* __restrict__ waA,
    float* __restrict__ biasF)
{
    const int tid = threadIdx.x;
    for (int i = tid; i < 2048; i += 256) {
        const int d = i >> 5, c = i & 31;
        float aq = 0.f, ak = 0.f;
#pragma unroll
        for (int k = 0; k < 32; ++k) {
            const float w1 = W1[d * 32 + k];
            aq = fmaf(w1, Wqkv[k * 32 + c], aq);
            ak = fmaf(w1, Wqkv[(32 + k) * 32 + c], ak);
        }
        Wq1[i] = aq;
        Wk1[i] = ak;
    }
    // W2 A-fragments (prescaled by log2e) for attn
    for (int i = tid; i < 1024; i += 256) {
        const int w = i & 3;
        const int lane = (i >> 2) & 63;
        const int kb = (i >> 8) & 1;
        const int ct = (i >> 9) & 1;
        const int row = (lane & 15) + 16 * ct;
        const int k0 = kb * 32 + ((lane >> 4) & 3) * 8 + 2 * w;
        W2A[i] = packbf2(W2[row * 64 + k0] * LOG2E, W2[row * 64 + k0 + 1] * LOG2E);
    }
    __syncthreads();
    // Wall A-fragments: i = (t*64+l)*4 + w2 ; row=16t+(l&15), k0=(l>>4)*8+2*w2
    for (int i = tid; i < 3072; i += 256) {
        const int t = i >> 8;
        const int l = (i >> 2) & 63;
        const int w2 = i & 3;
        const int row = 16 * t + (l & 15);
        const int k0 = ((l >> 4) & 3) * 8 + 2 * w2;
        float a0, a1;
        if (row < 64)        { a0 = Wk1[row * 32 + k0];            a1 = Wk1[row * 32 + k0 + 1]; }
        else if (row < 128)  { a0 = Wq1[(row - 64) * 32 + k0];     a1 = Wq1[(row - 64) * 32 + k0 + 1]; }
        else if (row < 160)  { a0 = Wqkv[(row - 64) * 32 + k0];    a1 = Wqkv[(row - 64) * 32 + k0 + 1]; }
        else {
            const int gr = row - 160;
            a0 = Wg[gr * 32 + k0]     + ((gr == k0)     ? 1.f : 0.f);
            a1 = Wg[gr * 32 + k0 + 1] + ((gr == k0 + 1) ? 1.f : 0.f);
        }
        waA[i] = packbf2(a0, a1);
    }
    // bias fragments: i = (t*64+l)*4 + r ; row = 16t + (l>>4)*4 + r
    for (int i = tid; i < 3072; i += 256) {
        const int t = i >> 8;
        const int l = (i >> 2) & 63;
        const int r = i & 3;
        const int row = 16 * t + ((l >> 4) & 3) * 4 + r;
        float bv = 0.f;
        if (row >= 64 && row < 128) bv = b1v[row - 64];
        else if (row >= 160)        bv = bgv[row - 160];
        biasF[i] = bv;
    }
}

// ---------------- kernel 1: MFMA projections ----------------
// Block = one image row (256 px), 4 waves; wave w owns px 64w..64w+63.
// LDS: x^T bf16 [256 px][64 B], 16B chunks rotated by ((chunk+px)&3).
// Zero barriers (wave-local staging + reads).
__global__ __launch_bounds__(256) void kv_kernel(
    const float* __restrict__ x, const short8* __restrict__ waA,
    const float4* __restrict__ biasF, unsigned* __restrict__ khP,
    unsigned* __restrict__ qhg, unsigned* __restrict__ vP,
    float* __restrict__ SkP, float* __restrict__ SqG,
    float* __restrict__ out)
{
    const int bid = blockIdx.x;
    const int tid = threadIdx.x;

    if (bid >= 1024) {
        // border zeroing: 4112 border pixels (1028 per batch)
        const int t = (bid - 1024) * 256 + tid;
        if (t < 4112) {
            const int bb = t / 1028;
            const int rr = t - bb * 1028;
            int hh, ww;
            if (rr < 258)      { hh = 0;             ww = rr; }
            else if (rr < 516) { hh = 257;           ww = rr - 258; }
            else if (rr < 772) { hh = rr - 516 + 1;  ww = 0; }
            else               { hh = rr - 772 + 1;  ww = 257; }
            const size_t pixP = (size_t)bb * PHW + hh * PW + ww;
            uint4* kp = (uint4*)khP + pixP * 8;
            uint4* vp = (uint4*)vP + pixP * 4;
            const uint4 z = { 0u, 0u, 0u, 0u };
#pragma unroll
            for (int i = 0; i < 8; ++i) kp[i] = z;
#pragma unroll
            for (int i = 0; i < 4; ++i) vp[i] = z;
            SkP[pixP] = 0.f;
        }
        return;
    }

    __shared__ __align__(16) unsigned xT[256 * 16];   // 16 KB

    const int b = bid >> 8;
    const int h = bid & 255;
    const int pix0 = bid * 256;                        // global pixel base
    const int rowP0 = b * PHW + (h + 1) * PW + 1;      // padded base (+px)

    // ---- stage own pixel's x -> bf16 LDS (chunk-rotated) ----
    {
        const float* xp = x + (size_t)b * (32 * HWm) + h * 256 + tid;
        float xv[32];
#pragma unroll
        for (int c = 0; c < 32; ++c) xv[c] = xp[c * HWm];
        unsigned* myx = &xT[tid * 16];
#pragma unroll
        for (int cc = 0; cc < 4; ++cc) {
            uint4 u;
            u.x = cvtpk(xv[cc * 8 + 0], xv[cc * 8 + 1]);
            u.y = cvtpk(xv[cc * 8 + 2], xv[cc * 8 + 3]);
            u.z = cvtpk(xv[cc * 8 + 4], xv[cc * 8 + 5]);
            u.w = cvtpk(xv[cc * 8 + 6], xv[cc * 8 + 7]);
            *(uint4*)(myx + (((cc + tid) & 3) * 4)) = u;
        }
    }
    // no barrier: wave w's MFMA B-reads touch only px 64w..64w+63 (own wave's writes)

    const int l = tid & 63;
    const int wid = tid >> 6;
    const int g = l >> 4;
    const int c15 = l & 15;

    short8 A[12];
    f32x4 bF[12];
#pragma unroll
    for (int t = 0; t < 12; ++t) {
        A[t] = waA[t * 64 + l];
        const float4 bv = biasF[t * 64 + l];
        bF[t][0] = bv.x; bF[t][1] = bv.y; bF[t][2] = bv.z; bF[t][3] = bv.w;
    }

#pragma unroll
    for (int pp = 0; pp < 4; ++pp) {
        const int pg = wid * 4 + pp;
        const int px = pg * 16 + c15;
        const short8 bfrag = *(const short8*)&xT[px * 16 + (((g + px) & 3) * 4)];

        f32x4 Ct[12];
#pragma unroll
        for (int t = 0; t < 12; ++t)
            Ct[t] = __builtin_amdgcn_mfma_f32_16x16x32_bf16(A[t], bfrag, bF[t], 0, 0, 0);

        const size_t pixP = (size_t)(rowP0 + px);
        const int pixg = pix0 + px;

        // kh: tiles 0-3 -> padded record, 8B per tile at byte t*32 + g*8
        float sk = 0.f;
        {
            char* krec = (char*)khP + pixP * 128 + g * 8;
#pragma unroll
            for (int t = 0; t < 4; ++t) {
                const unsigned u0 = cvtpk(Ct[t][0], Ct[t][1]);
                const unsigned u1 = cvtpk(Ct[t][2], Ct[t][3]);
                uint2 uu; uu.x = u0; uu.y = u1;
                *(uint2*)(krec + t * 32) = uu;
                sk += bflo(u0) + bfhi(u0) + bflo(u1) + bfhi(u1);
            }
        }
        // qh: tiles 4-7 -> unpadded record
        float sq = 0.f;
        {
            char* qrec = (char*)qhg + (size_t)pixg * 128 + g * 8;
#pragma unroll
            for (int t = 4; t < 8; ++t) {
                const unsigned u0 = cvtpk(Ct[t][0], Ct[t][1]);
                const unsigned u1 = cvtpk(Ct[t][2], Ct[t][3]);
                uint2 uu; uu.x = u0; uu.y = u1;
                *(uint2*)(qrec + (t - 4) * 32) = uu;
                sq += bflo(u0) + bfhi(u0) + bflo(u1) + bfhi(u1);
            }
        }
        // v: tiles 8-9 -> padded 64B record
        {
            char* vrec = (char*)vP + pixP * 64 + g * 8;
#pragma unroll
            for (int t = 8; t < 10; ++t) {
                const unsigned u0 = cvtpk(Ct[t][0], Ct[t][1]);
                const unsigned u1 = cvtpk(Ct[t][2], Ct[t][3]);
                uint2 uu; uu.x = u0; uu.y = u1;
                *(uint2*)(vrec + (t - 8) * 32) = uu;
            }
        }
        // gate+residual: tiles 10-11 -> out f32 channel-major
        {
            float* op = out + (size_t)b * (32 * HWm) + h * 256 + px;
#pragma unroll
            for (int t = 10; t < 12; ++t) {
#pragma unroll
                for (int r = 0; r < 4; ++r)
                    op[(16 * (t - 10) + g * 4 + r) * HWm] = Ct[t][r];
            }
        }
        // rounded sums -> Sk/Sq (reduce 4 lane-groups sharing a pixel)
        sk += __shfl_xor(sk, 16);
        sk += __shfl_xor(sk, 32);
        sq += __shfl_xor(sq, 16);
        sq += __shfl_xor(sq, 32);
        if (g == 0) {
            SkP[pixP] = sk;
            SqG[pixg] = sq;
        }
    }
}

// ---------------- kernel 2: MFMA attention (unchanged) ----------------
__global__ __launch_bounds__(256) void attn_kernel(
    const unsigned* __restrict__ qhg, const unsigned* __restrict__ khP,
    const unsigned* __restrict__ vP, const short8* __restrict__ w2a,
    const float* __restrict__ SkP, const float* __restrict__ SqG,
    const float* __restrict__ lnw, const float* __restrict__ lnb,
    const float* __restrict__ b2, float* __restrict__ out)
{
    __shared__ __align__(16) char hidL[32768];

    const int tid = threadIdx.x;
    const int bid = blockIdx.x;
    const int swz = (bid & 7) * 128 + (bid >> 3);
    const int b = swz >> 8;
    const int trem = swz & 255;
    const int h0 = (trem >> 4) << 4;
    const int w0 = (trem & 15) << 4;

    const int l = tid & 63;
    const int lane15 = tid & 15;
    const int q = (tid >> 4) & 3;
    const int wrow = tid >> 6;

    const int row = tid >> 4;
    const int h = h0 + row, w = w0 + lane15;
    const int pix = (b << 16) + (h << 8) + w;
    const int pixP = b * PHW + (h + 1) * PW + (w + 1);
    const int tileP = b * PHW + (h0 + 1) * PW + (w0 + 1);

    unsigned qw[32];
    {
        const uint4* qp = (const uint4*)qhg + (size_t)pix * 8;
#pragma unroll
        for (int i = 0; i < 8; ++i) {
            const uint4 u = qp[i];
            qw[4 * i] = u.x; qw[4 * i + 1] = u.y; qw[4 * i + 2] = u.z; qw[4 * i + 3] = u.w;
        }
    }
    const float Sq = SqG[pix];

    const short8 a00 = w2a[0 * 64 + l];
    const short8 a01 = w2a[1 * 64 + l];
    const short8 a10 = w2a[2 * 64 + l];
    const short8 a11 = w2a[3 * 64 + l];

    float b2v[8];
    {
        const float4 t0 = *(const float4*)(b2 + q * 4);
        const float4 t1 = *(const float4*)(b2 + 16 + q * 4);
        b2v[0] = t0.x * LOG2E; b2v[1] = t0.y * LOG2E; b2v[2] = t0.z * LOG2E; b2v[3] = t0.w * LOG2E;
        b2v[4] = t1.x * LOG2E; b2v[5] = t1.y * LOG2E; b2v[6] = t1.z * LOG2E; b2v[7] = t1.w * LOG2E;
    }

    float ssum[32], wv[32];
#pragma unroll
    for (int i = 0; i < 32; ++i) { ssum[i] = 0.f; wv[i] = 0.f; }

    const uint4* khP4 = (const uint4*)khP;
    char* const myhid = hidL + tid * 128;
    const int myswz = (tid & 7) << 4;

#pragma unroll
    for (int n = 0; n < 9; ++n) {
        const int dy = n / 3 - 1, dx = n % 3 - 1;

        const int nofs = pixP + dy * PW + dx;
        const uint4* kp = khP4 + (size_t)nofs * 8;
        const float Sk = SkP[nofs];
        float ss0 = 0.f, ss1 = 0.f, ss2 = 0.f, ss3 = 0.f;
        uint4 hw[8];
#pragma unroll
        for (int cj = 0; cj < 8; ++cj) {
            const uint4 kc = kp[cj];
            float hd[8];
            hd[0] = bflo(qw[cj * 4 + 0]) - bflo(kc.x);
            hd[1] = bfhi(qw[cj * 4 + 0]) - bfhi(kc.x);
            hd[2] = bflo(qw[cj * 4 + 1]) - bflo(kc.y);
            hd[3] = bfhi(qw[cj * 4 + 1]) - bfhi(kc.y);
            hd[4] = bflo(qw[cj * 4 + 2]) - bflo(kc.z);
            hd[5] = bfhi(qw[cj * 4 + 2]) - bfhi(kc.z);
            hd[6] = bflo(qw[cj * 4 + 3]) - bflo(kc.w);
            hd[7] = bfhi(qw[cj * 4 + 3]) - bfhi(kc.w);
            ss0 = fmaf(hd[0], hd[0], ss0); ss1 = fmaf(hd[1], hd[1], ss1);
            ss2 = fmaf(hd[2], hd[2], ss2); ss3 = fmaf(hd[3], hd[3], ss3);
            ss0 = fmaf(hd[4], hd[4], ss0); ss1 = fmaf(hd[5], hd[5], ss1);
            ss2 = fmaf(hd[6], hd[6], ss2); ss3 = fmaf(hd[7], hd[7], ss3);
            uint4 o;
            o.x = cvtpk(hd[0], hd[1]); o.y = cvtpk(hd[2], hd[3]);
            o.z = cvtpk(hd[4], hd[5]); o.w = cvtpk(hd[6], hd[7]);
            hw[cj] = o;
        }
        const float sum = Sq - Sk;
        const float sumsq = (ss0 + ss1) + (ss2 + ss3);
        const float mean = sum * 0.015625f;
        float var = fmaf(-mean, mean, sumsq * 0.015625f);
        var = fmaxf(var, 0.f);
        const float inv = __builtin_amdgcn_rcpf(sqrtf(var) + 1e-5f);
        const float nmi = -mean * inv;

#pragma unroll
        for (int cj = 0; cj < 8; ++cj) {
            const uint4 t = hw[cj];
            float hv[8];
            hv[0] = bflo(t.x); hv[1] = bfhi(t.x);
            hv[2] = bflo(t.y); hv[3] = bfhi(t.y);
            hv[4] = bflo(t.z); hv[5] = bfhi(t.z);
            hv[6] = bflo(t.w); hv[7] = bfhi(t.w);
#pragma unroll
            for (int j = 0; j < 8; ++j) {
                float tv = fmaf(hv[j], inv, nmi);
                tv = fmaf(tv, lnw[cj * 8 + j], lnb[cj * 8 + j]);
                hv[j] = fmaxf(tv, 0.f);
            }
            uint4 o;
            o.x = cvtpk(hv[0], hv[1]); o.y = cvtpk(hv[2], hv[3]);
            o.z = cvtpk(hv[4], hv[5]); o.w = cvtpk(hv[6], hv[7]);
            *(uint4*)(myhid + ((cj * 16) ^ myswz)) = o;
        }

#pragma unroll
        for (int gg = 0; gg < 4; ++gg) {
            const int g = wrow * 4 + gg;
            const int px = g * 16 + lane15;
            const char* bp = hidL + px * 128;
            const int sw = (lane15 & 7) << 4;
            const short8 b0 = *(const short8*)(bp + ((q * 16) ^ sw));
            const short8 b1 = *(const short8*)(bp + (((4 + q) * 16) ^ sw));
            f32x4 acc0 = { b2v[0], b2v[1], b2v[2], b2v[3] };
            f32x4 acc1 = { b2v[4], b2v[5], b2v[6], b2v[7] };
            acc0 = __builtin_amdgcn_mfma_f32_16x16x32_bf16(a00, b0, acc0, 0, 0, 0);
            acc0 = __builtin_amdgcn_mfma_f32_16x16x32_bf16(a01, b1, acc0, 0, 0, 0);
            acc1 = __builtin_amdgcn_mfma_f32_16x16x32_bf16(a10, b0, acc1, 0, 0, 0);
            acc1 = __builtin_amdgcn_mfma_f32_16x16x32_bf16(a11, b1, acc1, 0, 0, 0);

            const int npP = tileP + (g + dy) * PW + (lane15 + dx);
            const unsigned* vp = vP + (size_t)npP * 16;
            const uint2 vA = *(const uint2*)(vp + q * 2);
            const uint2 vB = *(const uint2*)(vp + 8 + q * 2);
            const float va[4] = { bflo(vA.x), bfhi(vA.x), bflo(vA.y), bfhi(vA.y) };
            const float vb[4] = { bflo(vB.x), bfhi(vB.x), bflo(vB.y), bfhi(vB.y) };
#pragma unroll
            for (int r = 0; r < 4; ++r) {
                const float e0 = __builtin_amdgcn_exp2f(acc0[r]);
                ssum[gg * 8 + r] += e0;
                wv[gg * 8 + r] = fmaf(e0, va[r], wv[gg * 8 + r]);
                const float e1 = __builtin_amdgcn_exp2f(acc1[r]);
                ssum[gg * 8 + 4 + r] += e1;
                wv[gg * 8 + 4 + r] = fmaf(e1, vb[r], wv[gg * 8 + 4 + r]);
            }
        }
    }

#pragma unroll
    for (int gg = 0; gg < 4; ++gg) {
        const int g = wrow * 4 + gg;
        float* op = out + (size_t)b * (32 * HWm) + ((h0 + g) << 8) + (w0 + lane15);
#pragma unroll
        for (int r = 0; r < 4; ++r) {
            const int ch0 = q * 4 + r;
            const int ch1 = 16 + q * 4 + r;
            op[ch0 * HWm] += wv[gg * 8 + r] * __builtin_amdgcn_rcpf(ssum[gg * 8 + r]);
            op[ch1 * HWm] += wv[gg * 8 + 4 + r] * __builtin_amdgcn_rcpf(ssum[gg * 8 + 4 + r]);
        }
    }
}

extern "C" void kernel_launch(void* const* d_in, const int* in_sizes, int n_in,
                              void* d_out, int out_size, void* d_ws, size_t ws_size,
                              hipStream_t stream) {
    const float* x    = (const float*)d_in[0];
    const float* Wqkv = (const float*)d_in[1];
    const float* W1   = (const float*)d_in[2];
    const float* b1   = (const float*)d_in[3];
    const float* lnw  = (const float*)d_in[4];
    const float* lnb  = (const float*)d_in[5];
    const float* W2   = (const float*)d_in[6];
    const float* b2   = (const float*)d_in[7];
    const float* Wg   = (const float*)d_in[8];
    const float* bg   = (const float*)d_in[9];
    float* out = (float*)d_out;

    float* ws  = (float*)d_ws;
    float* Wk1 = ws;                                  // 2048 f32
    float* Wq1 = ws + 2048;                           // 2048 f32
    unsigned* W2A  = (unsigned*)(ws + 4096);          // 1024 u32
    unsigned* waA  = (unsigned*)(ws + 5120);          // 3072 u32
    float*    biasF = ws + 8192;                      // 3072 f32
    unsigned* khP = (unsigned*)(ws + 11264);          // 4*PHW*32 u32 (padded)
    unsigned* qhg = khP + (size_t)4 * PHW * 32;       // NPIX*32 u32
    unsigned* vP  = qhg + (size_t)NPIX * 32;          // 4*PHW*16 u32 (padded)
    float* SkP = (float*)(vP + (size_t)4 * PHW * 16); // 4*PHW f32 (padded)
    float* SqG = SkP + (size_t)4 * PHW;               // NPIX f32

    prep_kernel<<<1, 256, 0, stream>>>(Wqkv, W1, W2, b1, Wg, bg,
                                       Wk1, Wq1, W2A, waA, biasF);
    kv_kernel<<<1024 + 17, 256, 0, stream>>>(x, (const short8*)waA,
                                             (const float4*)biasF,
                                             khP, qhg, vP, SkP, SqG, out);
    attn_kernel<<<1024, 256, 0, stream>>>(qhg, khP, vP, (const short8*)W2A,
                                          SkP, SqG, lnw, lnb, b2, out);
}